// Round 4
// baseline (9390.606 us; speedup 1.0000x reference)
//
#include <hip/hip_runtime.h>
#include <hip/hip_bf16.h>
#include <stdint.h>

using bf16 = __hip_bfloat16;
typedef __attribute__((ext_vector_type(8))) short short8;
typedef __attribute__((ext_vector_type(4))) float floatx4;

__device__ __forceinline__ float bf2f(bf16 v) { return __bfloat162float(v); }
__device__ __forceinline__ bf16 f2bf(float v) { return __float2bfloat16(v); }

__device__ __forceinline__ void gload16(const void* g, void* l) {
  __builtin_amdgcn_global_load_lds(
      (const __attribute__((address_space(1))) unsigned int*)g,
      (__attribute__((address_space(3))) unsigned int*)l, 16, 0, 0);
}

__device__ __forceinline__ float hsig(float x) {
  return fminf(fmaxf(0.2f * x + 0.5f, 0.f), 1.f);
}

__device__ __forceinline__ void store_out(float* p, float v) { *p = v; }
__device__ __forceinline__ void store_out(bf16* p, float v) { *p = f2bf(v); }

// ---------------------------------------------------------------------------
// Implicit-GEMM 5x5 SAME conv with split-bf16 (fp32-equivalent) arithmetic.
// Input frames: (n, 16, 21, 512) bf16, [hi(256) | lo(256)] per position,
// frame n at zin + n*stride_n.
// Weights: wt[kt][co][512], [W_hi(256) | W_lo(256)], kt = ky*5+kx.
// Virtual K = 12 blocks of 64: hi*Whi (4), hi*Wlo (4), lo*Whi (4).
// Output: out[row][co], row = n*336 + y*21 + x, ld 1024.
// Grid: (M/BM, 1024/BN), 256 threads (4 waves, 2x2).
// ---------------------------------------------------------------------------
template<int BM, int BN, typename OutT>
__global__ void __launch_bounds__(256) conv5x5s(
    const bf16* __restrict__ zin, long stride_n,
    const bf16* __restrict__ wt, const float* __restrict__ bias,
    OutT* __restrict__ out, const bf16* __restrict__ zerob)
{
  constexpr int BK = 64;
  constexpr int WM = BM / 2, WN = BN / 2;
  constexpr int FM = WM / 16, FN = WN / 16;
  constexpr int IA = BM / 32, IB = BN / 32;

  const int tid  = threadIdx.x;
  const int wave = tid >> 6;
  const int lane = tid & 63;
  const int wm = wave >> 1, wn = wave & 1;
  const int tm = blockIdx.x, tn = blockIdx.y;

  __shared__ short Asm_[BM * BK];
  __shared__ short Bsm_[BN * BK];

  int an[IA], ay[IA], ax[IA];
#pragma unroll
  for (int i = 0; i < IA; ++i) {
    int R = tm * BM + i * 32 + (tid >> 3);
    int n = R / 336;
    int rem = R - n * 336;
    int y = rem / 21;
    int x = rem - y * 21;
    an[i] = n; ay[i] = y; ax[i] = x;
  }
  const int eoff = (tid & 7) * 8;  // element offset for this lane's 16B chunk

  floatx4 acc[FM][FN];
  const floatx4 z4 = {0.f, 0.f, 0.f, 0.f};
#pragma unroll
  for (int a = 0; a < FM; ++a)
#pragma unroll
    for (int b = 0; b < FN; ++b)
      acc[a][b] = z4;

#pragma unroll 1
  for (int kt = 0; kt < 25; ++kt) {
    const int dy = kt / 5 - 2, dx = kt % 5 - 2;
    const bf16* abase[IA];
#pragma unroll
    for (int i = 0; i < IA; ++i) {
      int yy = ay[i] + dy, xx = ax[i] + dx;
      bool v = ((unsigned)yy < 16u) & ((unsigned)xx < 21u);
      abase[i] = v ? (zin + (long)an[i] * stride_n + (long)(yy * 21 + xx) * 512) : nullptr;
    }
#pragma unroll 1
    for (int cb = 0; cb < 12; ++cb) {
      const int j = cb & 3;
      const int a_cb = j + ((cb >= 8) ? 4 : 0);                 // lo for term 2
      const int b_cb = j + ((cb >= 4 && cb < 8) ? 4 : 0);       // Wlo for term 1
#pragma unroll
      for (int i = 0; i < IA; ++i) {
        const bf16* src = abase[i] ? (abase[i] + a_cb * 64 + eoff) : (zerob + eoff);
        gload16(src, &Asm_[(i * 32 + wave * 8) * BK]);
      }
#pragma unroll
      for (int i = 0; i < IB; ++i) {
        int brow = i * 32 + (tid >> 3);
        const bf16* src = wt + ((long)(kt * 1024 + tn * BN + brow)) * 512 + b_cb * 64 + eoff;
        gload16(src, &Bsm_[(i * 32 + wave * 8) * BK]);
      }
      __syncthreads();
#pragma unroll
      for (int ks = 0; ks < 2; ++ks) {
        short8 af[FM], bfv[FN];
#pragma unroll
        for (int f = 0; f < FM; ++f)
          af[f] = *(const short8*)&Asm_[(wm * WM + f * 16 + (lane & 15)) * BK + ks * 32 + (lane >> 4) * 8];
#pragma unroll
        for (int f = 0; f < FN; ++f)
          bfv[f] = *(const short8*)&Bsm_[(wn * WN + f * 16 + (lane & 15)) * BK + ks * 32 + (lane >> 4) * 8];
#pragma unroll
        for (int fm = 0; fm < FM; ++fm)
#pragma unroll
          for (int fn = 0; fn < FN; ++fn)
            acc[fm][fn] = __builtin_amdgcn_mfma_f32_16x16x32_bf16(af[fm], bfv[fn], acc[fm][fn], 0, 0, 0);
      }
      __syncthreads();
    }
  }

  const int orow0 = tm * BM + wm * WM;
  const int ocol0 = tn * BN + wn * WN;
#pragma unroll
  for (int fn = 0; fn < FN; ++fn) {
    int col = ocol0 + fn * 16 + (lane & 15);
    float bv = bias ? bias[col] : 0.f;
#pragma unroll
    for (int fm = 0; fm < FM; ++fm) {
      int row = orow0 + fm * 16 + (lane >> 4) * 4;
#pragma unroll
      for (int j2 = 0; j2 < 4; ++j2)
        store_out(out + (long)(row + j2) * 1024 + col, acc[fm][fn][j2] + bv);
    }
  }
}

// f32 (rows,256) -> split bf16 (rows,512) [hi|lo]
__global__ void splitcast(const float* __restrict__ in, bf16* __restrict__ out, int n) {
  int idx = blockIdx.x * 256 + threadIdx.x;
  if (idx >= n) return;
  int r = idx >> 8, c = idx & 255;
  float v = in[idx];
  bf16 hi = f2bf(v);
  out[(long)r * 512 + c] = hi;
  out[(long)r * 512 + 256 + c] = f2bf(v - bf2f(hi));
}

// weights (25,256,1024) f32 -> (25,1024,512) bf16 [W_hi | W_lo] (transposed)
__global__ void wtrans(const float* __restrict__ in, bf16* __restrict__ out) {
  __shared__ float t[32][33];
  int kt  = blockIdx.z;
  int cib = blockIdx.y;   // 8 tiles over ci=256
  int cob = blockIdx.x;   // 32 tiles over co=1024
  int c = threadIdx.x & 31;
  int r = threadIdx.x >> 5;
#pragma unroll
  for (int rr = 0; rr < 4; ++rr) {
    int row = r + rr * 8;
    t[row][c] = in[(long)(kt * 256 + cib * 32 + row) * 1024 + cob * 32 + c];
  }
  __syncthreads();
#pragma unroll
  for (int rr = 0; rr < 4; ++rr) {
    int row = r + rr * 8;
    float v = t[c][row];
    bf16 hi = f2bf(v);
    long o = (long)(kt * 1024 + cob * 32 + row) * 512 + cib * 32 + c;
    out[o] = hi;
    out[o + 256] = f2bf(v - bf2f(hi));
  }
}

// LSTM gate math for one timestep; h written hi/lo into (b,t,p,512).
__global__ void lstm_step(const float* __restrict__ xg, const float* __restrict__ g,
                          float* __restrict__ c, bf16* __restrict__ seqcat,
                          int t, int has_g)
{
  int idx = blockIdx.x * 256 + threadIdx.x;  // 344064 total
  int fc = idx & 255;
  int bp = idx >> 8;
  int b = bp / 336;
  int p = bp - b * 336;
  long xrow = ((long)(b * 16 + t) * 336 + p) * 1024;
  long grow = (long)bp * 1024;
  float gi = xg[xrow + fc];
  float gf = xg[xrow + 256 + fc];
  float gc = xg[xrow + 512 + fc];
  float go = xg[xrow + 768 + fc];
  if (has_g) {
    gi += g[grow + fc];
    gf += g[grow + 256 + fc];
    gc += g[grow + 512 + fc];
    go += g[grow + 768 + fc];
  }
  float i_ = hsig(gi), f_ = hsig(gf), o_ = hsig(go);
  float ccv = fmaxf(gc, 0.f);
  float cprev = has_g ? c[idx] : 0.f;
  float cn = f_ * cprev + i_ * ccv;
  float h = o_ * fmaxf(cn, 0.f);
  c[idx] = cn;
  long srow = ((long)(b * 16 + t) * 336 + p) * 512;
  bf16 hi = f2bf(h);
  seqcat[srow + fc] = hi;
  seqcat[srow + 256 + fc] = f2bf(h - bf2f(hi));
}

// per-(b,t) partial sums over the 336 spatial positions (reads hi+lo)
__global__ void inorm_stats1(const bf16* __restrict__ seqcat, float* __restrict__ psum,
                             float* __restrict__ psq) {
  int bt = blockIdx.x;       // 64
  int ch = threadIdx.x;      // 256
  long base = (long)bt * 172032 + ch;
  float s = 0.f, ss = 0.f;
  for (int p = 0; p < 336; ++p) {
    float v = bf2f(seqcat[base + p * 512]) + bf2f(seqcat[base + p * 512 + 256]);
    s += v; ss += v * v;
  }
  psum[bt * 256 + ch] = s;
  psq[bt * 256 + ch] = ss;
}

__global__ void inorm_stats2(const float* __restrict__ psum, const float* __restrict__ psq,
                             const float* __restrict__ gamma, const float* __restrict__ beta,
                             float* __restrict__ scale, float* __restrict__ shift) {
  int i = blockIdx.x * 256 + threadIdx.x;  // 1024: b*256+ch
  int ch = i & 255;
  int b = i >> 8;
  float s = 0.f, ss = 0.f;
  for (int t = 0; t < 16; ++t) {
    int o = (b * 16 + t) * 256 + ch;
    s += psum[o]; ss += psq[o];
  }
  float mu = s * (1.f / 5376.f);
  float var = fmaxf(ss * (1.f / 5376.f) - mu * mu, 0.f);
  float sc = gamma[ch] * rsqrtf(var + 1e-3f);
  scale[i] = sc;
  shift[i] = beta[ch] - mu * sc;
}

// reads seqcat (hi+lo), normalizes, writes split (rows,512) bf16 buffer
__global__ void inorm_apply_split(const bf16* __restrict__ seqcat, const float* __restrict__ scale,
                                  const float* __restrict__ shift, bf16* __restrict__ out) {
  int idx = blockIdx.x * 256 + threadIdx.x;  // 5505024
  int ch = idx & 255;
  int b = idx / 1376256;
  long srow = (long)(idx >> 8) * 512;
  float v = bf2f(seqcat[srow + ch]) + bf2f(seqcat[srow + 256 + ch]);
  v = v * scale[b * 256 + ch] + shift[b * 256 + ch];
  bf16 hi = f2bf(v);
  out[srow + ch] = hi;
  out[srow + 256 + ch] = f2bf(v - bf2f(hi));
}

// reads seqcat (hi+lo), normalizes, writes contiguous f32 output
__global__ void inorm_apply_f32(const bf16* __restrict__ seqcat, const float* __restrict__ scale,
                                const float* __restrict__ shift, float* __restrict__ out) {
  int idx = blockIdx.x * 256 + threadIdx.x;  // 5505024
  int ch = idx & 255;
  int b = idx / 1376256;
  long srow = (long)(idx >> 8) * 512;
  float v = bf2f(seqcat[srow + ch]) + bf2f(seqcat[srow + 256 + ch]);
  out[idx] = v * scale[b * 256 + ch] + shift[b * 256 + ch];
}

__global__ void finalize(const bf16* __restrict__ seqcat, const float* __restrict__ c,
                         float* __restrict__ h2, float* __restrict__ c2) {
  int idx = blockIdx.x * 256 + threadIdx.x;  // 344064
  int fc = idx & 255;
  int bp = idx >> 8;
  int b = bp / 336;
  int p = bp - b * 336;
  long srow = ((long)(b * 16 + 15) * 336 + p) * 512;
  h2[idx] = bf2f(seqcat[srow + fc]) + bf2f(seqcat[srow + 256 + fc]);
  c2[idx] = c[idx];
}

extern "C" void kernel_launch(void* const* d_in, const int* in_sizes, int n_in,
                              void* d_out, int out_size, void* d_ws, size_t ws_size,
                              hipStream_t stream) {
  const float* x   = (const float*)d_in[0];
  const float* k1  = (const float*)d_in[1];
  const float* rk1 = (const float*)d_in[2];
  const float* b1  = (const float*)d_in[3];
  const float* g1  = (const float*)d_in[4];
  const float* bt1 = (const float*)d_in[5];
  const float* k2  = (const float*)d_in[6];
  const float* rk2 = (const float*)d_in[7];
  const float* b2  = (const float*)d_in[8];
  const float* g2  = (const float*)d_in[9];
  const float* bt2 = (const float*)d_in[10];

  char* w = (char*)d_ws;
  auto carve = [&](size_t bytes) -> char* {
    char* p = w;
    w += (bytes + 255) & ~(size_t)255;
    return p;
  };
  bf16*  xc    = (bf16*)carve(11010048ull * 2);   // x split (21504,512)
  bf16*  k1c   = (bf16*)carve(13107200ull * 2);   // (25,1024,512) [hi|lo]
  bf16*  rk1c  = (bf16*)carve(13107200ull * 2);
  bf16*  k2c   = (bf16*)carve(13107200ull * 2);
  bf16*  rk2c  = (bf16*)carve(13107200ull * 2);
  float* xg    = (float*)carve(22020096ull * 4);  // f32 gate preactivations
  bf16*  seqc  = (bf16*)carve(11010048ull * 2);   // (b,t,p,512) hi/lo, reused both layers
  bf16*  seq1n = (bf16*)carve(11010048ull * 2);   // normalized layer-1 output, split
  float* gbuf  = (float*)carve(1376256ull * 4);
  float* cbuf  = (float*)carve(344064ull * 4);
  float* psum  = (float*)carve(16384ull * 4);
  float* psq   = (float*)carve(16384ull * 4);
  float* scal  = (float*)carve(1024ull * 4);
  float* shft  = (float*)carve(1024ull * 4);
  bf16*  zerob = (bf16*)carve(4096);

  hipMemsetAsync(zerob, 0, 4096, stream);

  splitcast<<<21504, 256, 0, stream>>>(x, xc, 5505024);
  dim3 tg(32, 8, 25);
  wtrans<<<tg, 256, 0, stream>>>(k1, k1c);
  wtrans<<<tg, 256, 0, stream>>>(rk1, rk1c);
  wtrans<<<tg, 256, 0, stream>>>(k2, k2c);
  wtrans<<<tg, 256, 0, stream>>>(rk2, rk2c);

  // ---- layer 1 ----
  conv5x5s<128, 128, float><<<dim3(168, 8), 256, 0, stream>>>(xc, 172032L, k1c, b1, xg, zerob);
  for (int t = 0; t < 16; ++t) {
    if (t > 0)
      conv5x5s<64, 64, float><<<dim3(21, 16), 256, 0, stream>>>(
          seqc + (long)(t - 1) * 172032, 2752512L, rk1c, nullptr, gbuf, zerob);
    lstm_step<<<1344, 256, 0, stream>>>(xg, gbuf, cbuf, seqc, t, t > 0 ? 1 : 0);
  }
  inorm_stats1<<<64, 256, 0, stream>>>(seqc, psum, psq);
  inorm_stats2<<<4, 256, 0, stream>>>(psum, psq, g1, bt1, scal, shft);
  inorm_apply_split<<<21504, 256, 0, stream>>>(seqc, scal, shft, seq1n);

  // ---- layer 2 ----
  conv5x5s<128, 128, float><<<dim3(168, 8), 256, 0, stream>>>(seq1n, 172032L, k2c, b2, xg, zerob);
  for (int t = 0; t < 16; ++t) {
    if (t > 0)
      conv5x5s<64, 64, float><<<dim3(21, 16), 256, 0, stream>>>(
          seqc + (long)(t - 1) * 172032, 2752512L, rk2c, nullptr, gbuf, zerob);
    lstm_step<<<1344, 256, 0, stream>>>(xg, gbuf, cbuf, seqc, t, t > 0 ? 1 : 0);
  }
  inorm_stats1<<<64, 256, 0, stream>>>(seqc, psum, psq);
  inorm_stats2<<<4, 256, 0, stream>>>(psum, psq, g2, bt2, scal, shft);

  float* outp = (float*)d_out;
  inorm_apply_f32<<<21504, 256, 0, stream>>>(seqc, scal, shft, outp);
  finalize<<<1344, 256, 0, stream>>>(seqc, cbuf, outp + 5505024, outp + 5505024 + 344064);
}

// Round 6
// 4626.730 us; speedup vs baseline: 2.0296x; 2.0296x over previous
//
#include <hip/hip_runtime.h>
#include <hip/hip_bf16.h>
#include <stdint.h>

using bf16 = __hip_bfloat16;
typedef __attribute__((ext_vector_type(8))) short short8;
typedef __attribute__((ext_vector_type(4))) float floatx4;

__device__ __forceinline__ float bf2f(bf16 v) { return __bfloat162float(v); }
__device__ __forceinline__ bf16 f2bf(float v) { return __float2bfloat16(v); }

__device__ __forceinline__ void gload16(const void* g, void* l) {
  __builtin_amdgcn_global_load_lds(
      (const __attribute__((address_space(1))) unsigned int*)g,
      (__attribute__((address_space(3))) unsigned int*)l, 16, 0, 0);
}

__device__ __forceinline__ float hsig(float x) {
  return fminf(fmaxf(0.2f * x + 0.5f, 0.f), 1.f);
}

__device__ __forceinline__ void store_out(float* p, float v) { *p = v; }
__device__ __forceinline__ void store_out(bf16* p, float v) { *p = f2bf(v); }

// ---------------------------------------------------------------------------
// Implicit-GEMM 5x5 SAME conv with split-bf16 (fp32-equivalent) arithmetic.
// Input frames: (n, 16, 21, 512) bf16, [hi(256) | lo(256)] per position.
// Weights: wt[kt][co][512], [W_hi | W_lo], kt = ky*5+kx.
// Virtual K = 12 blocks of 64: hi*Whi (4), hi*Wlo (4), lo*Whi (4).
// Split-K over taps: blockIdx.z handles kt in [z*KTS, (z+1)*KTS), writing
// to out + z*zstride. Output row = n*336 + y*21 + x, ld 1024.
// LDS tiles XOR-swizzled (byte ^= (row&7)<<4) via pre-swizzled global source
// (global_load_lds dest must stay linear) + swizzled ds_read address.
// ---------------------------------------------------------------------------
template<int BM, int BN, int KTS, typename OutT>
__global__ void __launch_bounds__(256) conv5x5s(
    const bf16* __restrict__ zin, long stride_n,
    const bf16* __restrict__ wt, const float* __restrict__ bias,
    OutT* __restrict__ out, long zstride, const bf16* __restrict__ zerob)
{
  constexpr int BK = 64;
  constexpr int WM = BM / 2, WN = BN / 2;
  constexpr int FM = WM / 16, FN = WN / 16;
  constexpr int IA = BM / 32, IB = BN / 32;

  const int tid  = threadIdx.x;
  const int wave = tid >> 6;
  const int lane = tid & 63;
  const int wm = wave >> 1, wn = wave & 1;
  const int tm = blockIdx.x, tn = blockIdx.y;
  const int kt0 = blockIdx.z * KTS;
  OutT* outp = out + (long)blockIdx.z * zstride;

  __shared__ short Asm_[BM * BK];
  __shared__ short Bsm_[BN * BK];

  int an[IA], ay[IA], ax[IA];
#pragma unroll
  for (int i = 0; i < IA; ++i) {
    int R = tm * BM + i * 32 + (tid >> 3);
    int n = R / 336;
    int rem = R - n * 336;
    int y = rem / 21;
    int x = rem - y * 21;
    an[i] = n; ay[i] = y; ax[i] = x;
  }
  // XOR-swizzled source chunk: lane writes LDS slot (tid&7) of row (tid>>3)&7;
  // that slot must hold global chunk (slot ^ row) for the swizzled read below.
  const int eoff = (((tid & 7) ^ ((tid >> 3) & 7))) * 8;  // elements

  floatx4 acc[FM][FN];
  const floatx4 z4 = {0.f, 0.f, 0.f, 0.f};
#pragma unroll
  for (int a = 0; a < FM; ++a)
#pragma unroll
    for (int b = 0; b < FN; ++b)
      acc[a][b] = z4;

#pragma unroll 1
  for (int kt = kt0; kt < kt0 + KTS; ++kt) {
    const int dy = kt / 5 - 2, dx = kt % 5 - 2;
    const bf16* abase[IA];
#pragma unroll
    for (int i = 0; i < IA; ++i) {
      int yy = ay[i] + dy, xx = ax[i] + dx;
      bool v = ((unsigned)yy < 16u) & ((unsigned)xx < 21u);
      abase[i] = v ? (zin + (long)an[i] * stride_n + (long)(yy * 21 + xx) * 512) : nullptr;
    }
#pragma unroll 1
    for (int cb = 0; cb < 12; ++cb) {
      const int j = cb & 3;
      const int a_cb = j + ((cb >= 8) ? 4 : 0);                 // lo for term 2
      const int b_cb = j + ((cb >= 4 && cb < 8) ? 4 : 0);       // Wlo for term 1
#pragma unroll
      for (int i = 0; i < IA; ++i) {
        const bf16* src = abase[i] ? (abase[i] + a_cb * 64 + eoff) : (zerob + eoff);
        gload16(src, &Asm_[(i * 32 + wave * 8) * BK]);
      }
#pragma unroll
      for (int i = 0; i < IB; ++i) {
        int brow = i * 32 + (tid >> 3);
        const bf16* src = wt + ((long)(kt * 1024 + tn * BN + brow)) * 512 + b_cb * 64 + eoff;
        gload16(src, &Bsm_[(i * 32 + wave * 8) * BK]);
      }
      __syncthreads();
#pragma unroll
      for (int ks = 0; ks < 2; ++ks) {
        short8 af[FM], bfv[FN];
#pragma unroll
        for (int f = 0; f < FM; ++f) {
          int ar = wm * WM + f * 16 + (lane & 15);
          int ab = (ks * 64 + (lane >> 4) * 16) ^ ((ar & 7) << 4);
          af[f] = *(const short8*)((const char*)Asm_ + ar * 128 + ab);
        }
#pragma unroll
        for (int f = 0; f < FN; ++f) {
          int br = wn * WN + f * 16 + (lane & 15);
          int bb = (ks * 64 + (lane >> 4) * 16) ^ ((br & 7) << 4);
          bfv[f] = *(const short8*)((const char*)Bsm_ + br * 128 + bb);
        }
#pragma unroll
        for (int fm = 0; fm < FM; ++fm)
#pragma unroll
          for (int fn = 0; fn < FN; ++fn)
            acc[fm][fn] = __builtin_amdgcn_mfma_f32_16x16x32_bf16(af[fm], bfv[fn], acc[fm][fn], 0, 0, 0);
      }
      __syncthreads();
    }
  }

  const int orow0 = tm * BM + wm * WM;
  const int ocol0 = tn * BN + wn * WN;
#pragma unroll
  for (int fn = 0; fn < FN; ++fn) {
    int col = ocol0 + fn * 16 + (lane & 15);
    float bv = bias ? bias[col] : 0.f;
#pragma unroll
    for (int fm = 0; fm < FM; ++fm) {
      int row = orow0 + fm * 16 + (lane >> 4) * 4;
#pragma unroll
      for (int j2 = 0; j2 < 4; ++j2)
        store_out(outp + (long)(row + j2) * 1024 + col, acc[fm][fn][j2] + bv);
    }
  }
}

// f32 (rows,256) -> split bf16 (rows,512) [hi|lo]
__global__ void splitcast(const float* __restrict__ in, bf16* __restrict__ out, int n) {
  int idx = blockIdx.x * 256 + threadIdx.x;
  if (idx >= n) return;
  int r = idx >> 8, c = idx & 255;
  float v = in[idx];
  bf16 hi = f2bf(v);
  out[(long)r * 512 + c] = hi;
  out[(long)r * 512 + 256 + c] = f2bf(v - bf2f(hi));
}

// weights (25,256,1024) f32 -> (25,1024,512) bf16 [W_hi | W_lo] (transposed)
__global__ void wtrans(const float* __restrict__ in, bf16* __restrict__ out) {
  __shared__ float t[32][33];
  int kt  = blockIdx.z;
  int cib = blockIdx.y;   // 8 tiles over ci=256
  int cob = blockIdx.x;   // 32 tiles over co=1024
  int c = threadIdx.x & 31;
  int r = threadIdx.x >> 5;
#pragma unroll
  for (int rr = 0; rr < 4; ++rr) {
    int row = r + rr * 8;
    t[row][c] = in[(long)(kt * 256 + cib * 32 + row) * 1024 + cob * 32 + c];
  }
  __syncthreads();
#pragma unroll
  for (int rr = 0; rr < 4; ++rr) {
    int row = r + rr * 8;
    float v = t[c][row];
    bf16 hi = f2bf(v);
    long o = (long)(kt * 1024 + cob * 32 + row) * 512 + cib * 32 + c;
    out[o] = hi;
    out[o + 256] = f2bf(v - bf2f(hi));
  }
}

// LSTM gate math for one timestep; sums 5 split-K partials; h written hi/lo.
__global__ void lstm_step(const float* __restrict__ xg, const float* __restrict__ gp,
                          float* __restrict__ c, bf16* __restrict__ seqcat,
                          int t, int has_g)
{
  int idx = blockIdx.x * 256 + threadIdx.x;  // 344064 total
  int fc = idx & 255;
  int bp = idx >> 8;
  int b = bp / 336;
  int p = bp - b * 336;
  long xrow = ((long)(b * 16 + t) * 336 + p) * 1024;
  long grow = (long)bp * 1024;
  float gi = xg[xrow + fc];
  float gf = xg[xrow + 256 + fc];
  float gc = xg[xrow + 512 + fc];
  float go = xg[xrow + 768 + fc];
  if (has_g) {
#pragma unroll
    for (int z = 0; z < 5; ++z) {
      const float* g = gp + (long)z * 1376256;
      gi += g[grow + fc];
      gf += g[grow + 256 + fc];
      gc += g[grow + 512 + fc];
      go += g[grow + 768 + fc];
    }
  }
  float i_ = hsig(gi), f_ = hsig(gf), o_ = hsig(go);
  float ccv = fmaxf(gc, 0.f);
  float cprev = has_g ? c[idx] : 0.f;
  float cn = f_ * cprev + i_ * ccv;
  float h = o_ * fmaxf(cn, 0.f);
  c[idx] = cn;
  long srow = ((long)(b * 16 + t) * 336 + p) * 512;
  bf16 hi = f2bf(h);
  seqcat[srow + fc] = hi;
  seqcat[srow + 256 + fc] = f2bf(h - bf2f(hi));
}

// per-(b,t) partial sums over the 336 spatial positions (reads hi+lo)
__global__ void inorm_stats1(const bf16* __restrict__ seqcat, float* __restrict__ psum,
                             float* __restrict__ psq) {
  int bt = blockIdx.x;       // 64
  int ch = threadIdx.x;      // 256
  long base = (long)bt * 172032 + ch;
  float s = 0.f, ss = 0.f;
  for (int p = 0; p < 336; ++p) {
    float v = bf2f(seqcat[base + p * 512]) + bf2f(seqcat[base + p * 512 + 256]);
    s += v; ss += v * v;
  }
  psum[bt * 256 + ch] = s;
  psq[bt * 256 + ch] = ss;
}

__global__ void inorm_stats2(const float* __restrict__ psum, const float* __restrict__ psq,
                             const float* __restrict__ gamma, const float* __restrict__ beta,
                             float* __restrict__ scale, float* __restrict__ shift) {
  int i = blockIdx.x * 256 + threadIdx.x;  // 1024: b*256+ch
  int ch = i & 255;
  int b = i >> 8;
  float s = 0.f, ss = 0.f;
  for (int t = 0; t < 16; ++t) {
    int o = (b * 16 + t) * 256 + ch;
    s += psum[o]; ss += psq[o];
  }
  float mu = s * (1.f / 5376.f);
  float var = fmaxf(ss * (1.f / 5376.f) - mu * mu, 0.f);
  float sc = gamma[ch] * rsqrtf(var + 1e-3f);
  scale[i] = sc;
  shift[i] = beta[ch] - mu * sc;
}

// normalizes seqcat IN-PLACE (each thread owns its hi/lo pair)
__global__ void inorm_apply_inplace(bf16* __restrict__ seqcat, const float* __restrict__ scale,
                                    const float* __restrict__ shift) {
  int idx = blockIdx.x * 256 + threadIdx.x;  // 5505024
  int ch = idx & 255;
  int b = idx / 1376256;
  long srow = (long)(idx >> 8) * 512;
  float v = bf2f(seqcat[srow + ch]) + bf2f(seqcat[srow + 256 + ch]);
  v = v * scale[b * 256 + ch] + shift[b * 256 + ch];
  bf16 hi = f2bf(v);
  seqcat[srow + ch] = hi;
  seqcat[srow + 256 + ch] = f2bf(v - bf2f(hi));
}

// reads seqcat (hi+lo), normalizes, writes contiguous f32 output
__global__ void inorm_apply_f32(const bf16* __restrict__ seqcat, const float* __restrict__ scale,
                                const float* __restrict__ shift, float* __restrict__ out) {
  int idx = blockIdx.x * 256 + threadIdx.x;  // 5505024
  int ch = idx & 255;
  int b = idx / 1376256;
  long srow = (long)(idx >> 8) * 512;
  float v = bf2f(seqcat[srow + ch]) + bf2f(seqcat[srow + 256 + ch]);
  out[idx] = v * scale[b * 256 + ch] + shift[b * 256 + ch];
}

__global__ void finalize(const bf16* __restrict__ seqcat, const float* __restrict__ c,
                         float* __restrict__ h2, float* __restrict__ c2) {
  int idx = blockIdx.x * 256 + threadIdx.x;  // 344064
  int fc = idx & 255;
  int bp = idx >> 8;
  int b = bp / 336;
  int p = bp - b * 336;
  long srow = ((long)(b * 16 + 15) * 336 + p) * 512;
  h2[idx] = bf2f(seqcat[srow + fc]) + bf2f(seqcat[srow + 256 + fc]);
  c2[idx] = c[idx];
}

extern "C" void kernel_launch(void* const* d_in, const int* in_sizes, int n_in,
                              void* d_out, int out_size, void* d_ws, size_t ws_size,
                              hipStream_t stream) {
  const float* x   = (const float*)d_in[0];
  const float* k1  = (const float*)d_in[1];
  const float* rk1 = (const float*)d_in[2];
  const float* b1  = (const float*)d_in[3];
  const float* g1  = (const float*)d_in[4];
  const float* bt1 = (const float*)d_in[5];
  const float* k2  = (const float*)d_in[6];
  const float* rk2 = (const float*)d_in[7];
  const float* b2  = (const float*)d_in[8];
  const float* g2  = (const float*)d_in[9];
  const float* bt2 = (const float*)d_in[10];

  char* w = (char*)d_ws;
  auto carve = [&](size_t bytes) -> char* {
    char* p = w;
    w += (bytes + 255) & ~(size_t)255;
    return p;
  };
  bf16*  xc    = (bf16*)carve(11010048ull * 2);   // x split (21504,512)
  bf16*  k1c   = (bf16*)carve(13107200ull * 2);   // (25,1024,512) [hi|lo]
  bf16*  rk1c  = (bf16*)carve(13107200ull * 2);
  bf16*  k2c   = (bf16*)carve(13107200ull * 2);
  bf16*  rk2c  = (bf16*)carve(13107200ull * 2);
  float* xg    = (float*)carve(22020096ull * 4);  // f32 gate preactivations
  bf16*  seqc  = (bf16*)carve(11010048ull * 2);   // (b,t,p,512) hi/lo, reused both layers
  float* gpart = (float*)carve(5ull * 1376256ull * 4);  // split-K partials
  float* cbuf  = (float*)carve(344064ull * 4);
  float* psum  = (float*)carve(16384ull * 4);
  float* psq   = (float*)carve(16384ull * 4);
  float* scal  = (float*)carve(1024ull * 4);
  float* shft  = (float*)carve(1024ull * 4);
  bf16*  zerob = (bf16*)carve(4096);

  hipMemsetAsync(zerob, 0, 4096, stream);

  splitcast<<<21504, 256, 0, stream>>>(x, xc, 5505024);
  dim3 tg(32, 8, 25);
  wtrans<<<tg, 256, 0, stream>>>(k1, k1c);
  wtrans<<<tg, 256, 0, stream>>>(rk1, rk1c);
  wtrans<<<tg, 256, 0, stream>>>(k2, k2c);
  wtrans<<<tg, 256, 0, stream>>>(rk2, rk2c);

  // ---- layer 1 ----
  conv5x5s<128, 128, 25, float><<<dim3(168, 8, 1), 256, 0, stream>>>(
      xc, 172032L, k1c, b1, xg, 0L, zerob);
  for (int t = 0; t < 16; ++t) {
    if (t > 0)
      conv5x5s<64, 64, 5, float><<<dim3(21, 16, 5), 256, 0, stream>>>(
          seqc + (long)(t - 1) * 172032, 2752512L, rk1c, nullptr, gpart, 1376256L, zerob);
    lstm_step<<<1344, 256, 0, stream>>>(xg, gpart, cbuf, seqc, t, t > 0 ? 1 : 0);
  }
  inorm_stats1<<<64, 256, 0, stream>>>(seqc, psum, psq);
  inorm_stats2<<<4, 256, 0, stream>>>(psum, psq, g1, bt1, scal, shft);
  inorm_apply_inplace<<<21504, 256, 0, stream>>>(seqc, scal, shft);

  // ---- layer 2 ----
  conv5x5s<128, 128, 25, float><<<dim3(168, 8, 1), 256, 0, stream>>>(
      seqc, 172032L, k2c, b2, xg, 0L, zerob);
  for (int t = 0; t < 16; ++t) {
    if (t > 0)
      conv5x5s<64, 64, 5, float><<<dim3(21, 16, 5), 256, 0, stream>>>(
          seqc + (long)(t - 1) * 172032, 2752512L, rk2c, nullptr, gpart, 1376256L, zerob);
    lstm_step<<<1344, 256, 0, stream>>>(xg, gpart, cbuf, seqc, t, t > 0 ? 1 : 0);
  }
  inorm_stats1<<<64, 256, 0, stream>>>(seqc, psum, psq);
  inorm_stats2<<<4, 256, 0, stream>>>(psum, psq, g2, bt2, scal, shft);

  float* outp = (float*)d_out;
  inorm_apply_f32<<<21504, 256, 0, stream>>>(seqc, scal, shft, outp);
  finalize<<<1344, 256, 0, stream>>>(seqc, cbuf, outp + 5505024, outp + 5505024 + 344064);
}

// Round 7
// 3954.774 us; speedup vs baseline: 2.3745x; 1.1699x over previous
//
#include <hip/hip_runtime.h>
#include <hip/hip_bf16.h>
#include <stdint.h>

using bf16 = __hip_bfloat16;
typedef __attribute__((ext_vector_type(8))) short short8;
typedef __attribute__((ext_vector_type(4))) float floatx4;

__device__ __forceinline__ float bf2f(bf16 v) { return __bfloat162float(v); }
__device__ __forceinline__ bf16 f2bf(float v) { return __float2bfloat16(v); }

__device__ __forceinline__ void gload16(const void* g, void* l) {
  __builtin_amdgcn_global_load_lds(
      (const __attribute__((address_space(1))) unsigned int*)g,
      (__attribute__((address_space(3))) unsigned int*)l, 16, 0, 0);
}

__device__ __forceinline__ float hsig(float x) {
  return fminf(fmaxf(0.2f * x + 0.5f, 0.f), 1.f);
}

__device__ __forceinline__ void store_out(float* p, float v) { *p = v; }
__device__ __forceinline__ void store_out(bf16* p, float v) { *p = f2bf(v); }

// ---------------------------------------------------------------------------
// Implicit-GEMM 5x5 SAME conv with split-bf16 arithmetic.
// Input frames: (n, 16, 21, 512) bf16, [hi(256) | lo(256)] per position.
// Weights: wt[kt][co][512], [W_hi | W_lo], kt = ky*5+kx.
// Virtual K = NCB blocks of 64:
//   NCB=12 (fp32-equivalent): hi*Whi (4), hi*Wlo (4), lo*Whi (4)
//   NCB=8  (2-term, input convs): hi*Whi (4), hi*Wlo (4)
// Split-K over taps: blockIdx.z handles kt in [z*KTS, (z+1)*KTS), writing
// to out + z*zstride. Output row = n*336 + y*21 + x, ld 1024.
// LDS tiles XOR-swizzled (byte ^= (row&7)<<4) via pre-swizzled global source
// (global_load_lds dest must stay linear) + swizzled ds_read address.
// ---------------------------------------------------------------------------
template<int BM, int BN, int KTS, int NCB, typename OutT>
__global__ void __launch_bounds__(256) conv5x5s(
    const bf16* __restrict__ zin, long stride_n,
    const bf16* __restrict__ wt, const float* __restrict__ bias,
    OutT* __restrict__ out, long zstride, const bf16* __restrict__ zerob)
{
  constexpr int BK = 64;
  constexpr int WM = BM / 2, WN = BN / 2;
  constexpr int FM = WM / 16, FN = WN / 16;
  constexpr int IA = BM / 32, IB = BN / 32;

  const int tid  = threadIdx.x;
  const int wave = tid >> 6;
  const int lane = tid & 63;
  const int wm = wave >> 1, wn = wave & 1;
  const int tm = blockIdx.x, tn = blockIdx.y;
  const int kt0 = blockIdx.z * KTS;
  OutT* outp = out + (long)blockIdx.z * zstride;

  __shared__ short Asm_[BM * BK];
  __shared__ short Bsm_[BN * BK];

  int an[IA], ay[IA], ax[IA];
#pragma unroll
  for (int i = 0; i < IA; ++i) {
    int R = tm * BM + i * 32 + (tid >> 3);
    int n = R / 336;
    int rem = R - n * 336;
    int y = rem / 21;
    int x = rem - y * 21;
    an[i] = n; ay[i] = y; ax[i] = x;
  }
  // XOR-swizzled source chunk: lane writes LDS slot (tid&7) of row (tid>>3)&7;
  // that slot must hold global chunk (slot ^ row) for the swizzled read below.
  const int eoff = (((tid & 7) ^ ((tid >> 3) & 7))) * 8;  // elements

  floatx4 acc[FM][FN];
  const floatx4 z4 = {0.f, 0.f, 0.f, 0.f};
#pragma unroll
  for (int a = 0; a < FM; ++a)
#pragma unroll
    for (int b = 0; b < FN; ++b)
      acc[a][b] = z4;

#pragma unroll 1
  for (int kt = kt0; kt < kt0 + KTS; ++kt) {
    const int dy = kt / 5 - 2, dx = kt % 5 - 2;
    const bf16* abase[IA];
#pragma unroll
    for (int i = 0; i < IA; ++i) {
      int yy = ay[i] + dy, xx = ax[i] + dx;
      bool v = ((unsigned)yy < 16u) & ((unsigned)xx < 21u);
      abase[i] = v ? (zin + (long)an[i] * stride_n + (long)(yy * 21 + xx) * 512) : nullptr;
    }
#pragma unroll 1
    for (int cb = 0; cb < NCB; ++cb) {
      const int j = cb & 3;
      const int a_cb = j + ((cb >= 8) ? 4 : 0);                 // lo for term 3
      const int b_cb = j + ((cb >= 4 && cb < 8) ? 4 : 0);       // Wlo for term 2
#pragma unroll
      for (int i = 0; i < IA; ++i) {
        const bf16* src = abase[i] ? (abase[i] + a_cb * 64 + eoff) : (zerob + eoff);
        gload16(src, &Asm_[(i * 32 + wave * 8) * BK]);
      }
#pragma unroll
      for (int i = 0; i < IB; ++i) {
        int brow = i * 32 + (tid >> 3);
        const bf16* src = wt + ((long)(kt * 1024 + tn * BN + brow)) * 512 + b_cb * 64 + eoff;
        gload16(src, &Bsm_[(i * 32 + wave * 8) * BK]);
      }
      __syncthreads();
#pragma unroll
      for (int ks = 0; ks < 2; ++ks) {
        short8 af[FM], bfv[FN];
#pragma unroll
        for (int f = 0; f < FM; ++f) {
          int ar = wm * WM + f * 16 + (lane & 15);
          int ab = (ks * 64 + (lane >> 4) * 16) ^ ((ar & 7) << 4);
          af[f] = *(const short8*)((const char*)Asm_ + ar * 128 + ab);
        }
#pragma unroll
        for (int f = 0; f < FN; ++f) {
          int br = wn * WN + f * 16 + (lane & 15);
          int bb = (ks * 64 + (lane >> 4) * 16) ^ ((br & 7) << 4);
          bfv[f] = *(const short8*)((const char*)Bsm_ + br * 128 + bb);
        }
#pragma unroll
        for (int fm = 0; fm < FM; ++fm)
#pragma unroll
          for (int fn = 0; fn < FN; ++fn)
            acc[fm][fn] = __builtin_amdgcn_mfma_f32_16x16x32_bf16(af[fm], bfv[fn], acc[fm][fn], 0, 0, 0);
      }
      __syncthreads();
    }
  }

  const int orow0 = tm * BM + wm * WM;
  const int ocol0 = tn * BN + wn * WN;
#pragma unroll
  for (int fn = 0; fn < FN; ++fn) {
    int col = ocol0 + fn * 16 + (lane & 15);
    float bv = bias ? bias[col] : 0.f;
#pragma unroll
    for (int fm = 0; fm < FM; ++fm) {
      int row = orow0 + fm * 16 + (lane >> 4) * 4;
#pragma unroll
      for (int j2 = 0; j2 < 4; ++j2)
        store_out(outp + (long)(row + j2) * 1024 + col, acc[fm][fn][j2] + bv);
    }
  }
}

// f32 (rows,256) -> split bf16 (rows,512) [hi|lo]
__global__ void splitcast(const float* __restrict__ in, bf16* __restrict__ out, int n) {
  int idx = blockIdx.x * 256 + threadIdx.x;
  if (idx >= n) return;
  int r = idx >> 8, c = idx & 255;
  float v = in[idx];
  bf16 hi = f2bf(v);
  out[(long)r * 512 + c] = hi;
  out[(long)r * 512 + 256 + c] = f2bf(v - bf2f(hi));
}

// weights (25,256,1024) f32 -> (25,1024,512) bf16 [W_hi | W_lo] (transposed)
__global__ void wtrans(const float* __restrict__ in, bf16* __restrict__ out) {
  __shared__ float t[32][33];
  int kt  = blockIdx.z;
  int cib = blockIdx.y;   // 8 tiles over ci=256
  int cob = blockIdx.x;   // 32 tiles over co=1024
  int c = threadIdx.x & 31;
  int r = threadIdx.x >> 5;
#pragma unroll
  for (int rr = 0; rr < 4; ++rr) {
    int row = r + rr * 8;
    t[row][c] = in[(long)(kt * 256 + cib * 32 + row) * 1024 + cob * 32 + c];
  }
  __syncthreads();
#pragma unroll
  for (int rr = 0; rr < 4; ++rr) {
    int row = r + rr * 8;
    float v = t[c][row];
    bf16 hi = f2bf(v);
    long o = (long)(kt * 1024 + cob * 32 + row) * 512 + cib * 32 + c;
    out[o] = hi;
    out[o + 256] = f2bf(v - bf2f(hi));
  }
}

// LSTM gate math for one timestep; sums 5 split-K partials; h written hi/lo.
__global__ void lstm_step(const float* __restrict__ xg, const float* __restrict__ gp,
                          float* __restrict__ c, bf16* __restrict__ seqcat,
                          int t, int has_g)
{
  int idx = blockIdx.x * 256 + threadIdx.x;  // 344064 total
  int fc = idx & 255;
  int bp = idx >> 8;
  int b = bp / 336;
  int p = bp - b * 336;
  long xrow = ((long)(b * 16 + t) * 336 + p) * 1024;
  long grow = (long)bp * 1024;
  float gi = xg[xrow + fc];
  float gf = xg[xrow + 256 + fc];
  float gc = xg[xrow + 512 + fc];
  float go = xg[xrow + 768 + fc];
  if (has_g) {
#pragma unroll
    for (int z = 0; z < 5; ++z) {
      const float* g = gp + (long)z * 1376256;
      gi += g[grow + fc];
      gf += g[grow + 256 + fc];
      gc += g[grow + 512 + fc];
      go += g[grow + 768 + fc];
    }
  }
  float i_ = hsig(gi), f_ = hsig(gf), o_ = hsig(go);
  float ccv = fmaxf(gc, 0.f);
  float cprev = has_g ? c[idx] : 0.f;
  float cn = f_ * cprev + i_ * ccv;
  float h = o_ * fmaxf(cn, 0.f);
  c[idx] = cn;
  long srow = ((long)(b * 16 + t) * 336 + p) * 512;
  bf16 hi = f2bf(h);
  seqcat[srow + fc] = hi;
  seqcat[srow + 256 + fc] = f2bf(h - bf2f(hi));
}

// per-(b,t) partial sums over the 336 spatial positions (reads hi+lo)
__global__ void inorm_stats1(const bf16* __restrict__ seqcat, float* __restrict__ psum,
                             float* __restrict__ psq) {
  int bt = blockIdx.x;       // 64
  int ch = threadIdx.x;      // 256
  long base = (long)bt * 172032 + ch;
  float s = 0.f, ss = 0.f;
  for (int p = 0; p < 336; ++p) {
    float v = bf2f(seqcat[base + p * 512]) + bf2f(seqcat[base + p * 512 + 256]);
    s += v; ss += v * v;
  }
  psum[bt * 256 + ch] = s;
  psq[bt * 256 + ch] = ss;
}

__global__ void inorm_stats2(const float* __restrict__ psum, const float* __restrict__ psq,
                             const float* __restrict__ gamma, const float* __restrict__ beta,
                             float* __restrict__ scale, float* __restrict__ shift) {
  int i = blockIdx.x * 256 + threadIdx.x;  // 1024: b*256+ch
  int ch = i & 255;
  int b = i >> 8;
  float s = 0.f, ss = 0.f;
  for (int t = 0; t < 16; ++t) {
    int o = (b * 16 + t) * 256 + ch;
    s += psum[o]; ss += psq[o];
  }
  float mu = s * (1.f / 5376.f);
  float var = fmaxf(ss * (1.f / 5376.f) - mu * mu, 0.f);
  float sc = gamma[ch] * rsqrtf(var + 1e-3f);
  scale[i] = sc;
  shift[i] = beta[ch] - mu * sc;
}

// normalizes seqcat IN-PLACE (each thread owns its hi/lo pair)
__global__ void inorm_apply_inplace(bf16* __restrict__ seqcat, const float* __restrict__ scale,
                                    const float* __restrict__ shift) {
  int idx = blockIdx.x * 256 + threadIdx.x;  // 5505024
  int ch = idx & 255;
  int b = idx / 1376256;
  long srow = (long)(idx >> 8) * 512;
  float v = bf2f(seqcat[srow + ch]) + bf2f(seqcat[srow + 256 + ch]);
  v = v * scale[b * 256 + ch] + shift[b * 256 + ch];
  bf16 hi = f2bf(v);
  seqcat[srow + ch] = hi;
  seqcat[srow + 256 + ch] = f2bf(v - bf2f(hi));
}

// reads seqcat (hi+lo), normalizes, writes contiguous f32 output
__global__ void inorm_apply_f32(const bf16* __restrict__ seqcat, const float* __restrict__ scale,
                                const float* __restrict__ shift, float* __restrict__ out) {
  int idx = blockIdx.x * 256 + threadIdx.x;  // 5505024
  int ch = idx & 255;
  int b = idx / 1376256;
  long srow = (long)(idx >> 8) * 512;
  float v = bf2f(seqcat[srow + ch]) + bf2f(seqcat[srow + 256 + ch]);
  out[idx] = v * scale[b * 256 + ch] + shift[b * 256 + ch];
}

__global__ void finalize(const bf16* __restrict__ seqcat, const float* __restrict__ c,
                         float* __restrict__ h2, float* __restrict__ c2) {
  int idx = blockIdx.x * 256 + threadIdx.x;  // 344064
  int fc = idx & 255;
  int bp = idx >> 8;
  int b = bp / 336;
  int p = bp - b * 336;
  long srow = ((long)(b * 16 + 15) * 336 + p) * 512;
  h2[idx] = bf2f(seqcat[srow + fc]) + bf2f(seqcat[srow + 256 + fc]);
  c2[idx] = c[idx];
}

extern "C" void kernel_launch(void* const* d_in, const int* in_sizes, int n_in,
                              void* d_out, int out_size, void* d_ws, size_t ws_size,
                              hipStream_t stream) {
  const float* x   = (const float*)d_in[0];
  const float* k1  = (const float*)d_in[1];
  const float* rk1 = (const float*)d_in[2];
  const float* b1  = (const float*)d_in[3];
  const float* g1  = (const float*)d_in[4];
  const float* bt1 = (const float*)d_in[5];
  const float* k2  = (const float*)d_in[6];
  const float* rk2 = (const float*)d_in[7];
  const float* b2  = (const float*)d_in[8];
  const float* g2  = (const float*)d_in[9];
  const float* bt2 = (const float*)d_in[10];

  char* w = (char*)d_ws;
  auto carve = [&](size_t bytes) -> char* {
    char* p = w;
    w += (bytes + 255) & ~(size_t)255;
    return p;
  };
  bf16*  xc    = (bf16*)carve(11010048ull * 2);   // x split (21504,512)
  bf16*  k1c   = (bf16*)carve(13107200ull * 2);   // (25,1024,512) [hi|lo]
  bf16*  rk1c  = (bf16*)carve(13107200ull * 2);
  bf16*  k2c   = (bf16*)carve(13107200ull * 2);
  bf16*  rk2c  = (bf16*)carve(13107200ull * 2);
  float* xg    = (float*)carve(22020096ull * 4);  // f32 gate preactivations
  bf16*  seqc  = (bf16*)carve(11010048ull * 2);   // (b,t,p,512) hi/lo, reused both layers
  float* gpart = (float*)carve(5ull * 1376256ull * 4);  // split-K partials
  float* cbuf  = (float*)carve(344064ull * 4);
  float* psum  = (float*)carve(16384ull * 4);
  float* psq   = (float*)carve(16384ull * 4);
  float* scal  = (float*)carve(1024ull * 4);
  float* shft  = (float*)carve(1024ull * 4);
  bf16*  zerob = (bf16*)carve(4096);

  hipMemsetAsync(zerob, 0, 4096, stream);

  splitcast<<<21504, 256, 0, stream>>>(x, xc, 5505024);
  dim3 tg(32, 8, 25);
  wtrans<<<tg, 256, 0, stream>>>(k1, k1c);
  wtrans<<<tg, 256, 0, stream>>>(rk1, rk1c);
  wtrans<<<tg, 256, 0, stream>>>(k2, k2c);
  wtrans<<<tg, 256, 0, stream>>>(rk2, rk2c);

  // ---- layer 1 ----
  conv5x5s<128, 128, 25, 8, float><<<dim3(168, 8, 1), 256, 0, stream>>>(
      xc, 172032L, k1c, b1, xg, 0L, zerob);
  for (int t = 0; t < 16; ++t) {
    if (t > 0)
      conv5x5s<64, 64, 5, 12, float><<<dim3(21, 16, 5), 256, 0, stream>>>(
          seqc + (long)(t - 1) * 172032, 2752512L, rk1c, nullptr, gpart, 1376256L, zerob);
    lstm_step<<<1344, 256, 0, stream>>>(xg, gpart, cbuf, seqc, t, t > 0 ? 1 : 0);
  }
  inorm_stats1<<<64, 256, 0, stream>>>(seqc, psum, psq);
  inorm_stats2<<<4, 256, 0, stream>>>(psum, psq, g1, bt1, scal, shft);
  inorm_apply_inplace<<<21504, 256, 0, stream>>>(seqc, scal, shft);

  // ---- layer 2 ----
  conv5x5s<128, 128, 25, 8, float><<<dim3(168, 8, 1), 256, 0, stream>>>(
      seqc, 172032L, k2c, b2, xg, 0L, zerob);
  for (int t = 0; t < 16; ++t) {
    if (t > 0)
      conv5x5s<64, 64, 5, 12, float><<<dim3(21, 16, 5), 256, 0, stream>>>(
          seqc + (long)(t - 1) * 172032, 2752512L, rk2c, nullptr, gpart, 1376256L, zerob);
    lstm_step<<<1344, 256, 0, stream>>>(xg, gpart, cbuf, seqc, t, t > 0 ? 1 : 0);
  }
  inorm_stats1<<<64, 256, 0, stream>>>(seqc, psum, psq);
  inorm_stats2<<<4, 256, 0, stream>>>(psum, psq, g2, bt2, scal, shft);

  float* outp = (float*)d_out;
  inorm_apply_f32<<<21504, 256, 0, stream>>>(seqc, scal, shft, outp);
  finalize<<<1344, 256, 0, stream>>>(seqc, cbuf, outp + 5505024, outp + 5505024 + 344064);
}